// Round 19
// baseline (637.834 us; speedup 1.0000x reference)
//
#include <hip/hip_runtime.h>

#define DI __device__ __forceinline__

typedef short bf16x8 __attribute__((ext_vector_type(8)));
typedef float f32x4  __attribute__((ext_vector_type(4)));

#define MFMA(a,b,c) __builtin_amdgcn_mfma_f32_16x16x32_bf16(a,b,c,0,0,0)

constexpr int    SZ_WT = 512*80;
constexpr int    SZ_WB = 512*96;
constexpr int    SZ_WF = 96*512;
constexpr int    SZ_WG = 512*512;
constexpr int    SZ_WC = 512*512;
constexpr size_t OFF_WT  = 0;
constexpr size_t OFF_WB  = OFF_WT + 3*(size_t)SZ_WT;     // 122880
constexpr size_t OFF_WF  = OFF_WB + 3*(size_t)SZ_WB;     // 270336
constexpr size_t OFF_WG  = OFF_WF + 3*(size_t)SZ_WF;     // 417792
constexpr size_t OFF_WC  = OFF_WG + 3*(size_t)SZ_WG;     // 1204224
constexpr size_t OFF_WH  = OFF_WC + 3*(size_t)SZ_WC;     // 1990656  [512][192] nhw1|dhw1|wtw1
constexpr size_t OFF_WH2 = OFF_WH + (size_t)512*192;     // 2088960  [128][256] blockdiag(nhw2,dhw2)
constexpr size_t WS_TOTAL= OFF_WH2 + (size_t)128*256;    // 2121728 bf16 elems

DI short f2b(float f){ unsigned u; __builtin_memcpy(&u,&f,4); u += 0x7fffu + ((u>>16)&1u); return (short)(u>>16); }
DI float b2f(short s){ unsigned u = ((unsigned)(unsigned short)s)<<16; float f; __builtin_memcpy(&f,&u,4); return f; }
DI float sigm(float x){ return 1.f/(1.f+__expf(-x)); }

// ---------------- weight prepass: fp32 -> bf16 MFMA-B-fragment layout ----------------
// frag element t = ((nt*K32 + kt)*64 + lane)*8 + j  <->  W[kt*32 + (lane>>4)*8 + j][nt*16 + (lane&15)]
__global__ __launch_bounds__(256) void prep_weights(
    const float* __restrict__ pbw,  const float* __restrict__ paw1,
    const float* __restrict__ piw1, const float* __restrict__ pfw,
    const float* __restrict__ pgw,  const float* __restrict__ fcw,
    const float* __restrict__ nhw1, const float* __restrict__ nhw2,
    const float* __restrict__ dhw1, const float* __restrict__ dhw2,
    const float* __restrict__ wtw1, short* __restrict__ ws)
{
  size_t t = (size_t)blockIdx.x*256 + threadIdx.x;
  if (t >= WS_TOTAL) return;
  float v = 0.f;
  if (t < OFF_WB) {                                   // [512][80] = paw1 | piw1, K32=16
    int q=(int)t; int ly=q/SZ_WT; int qq=q%SZ_WT;
    int j=qq&7, lane=(qq>>3)&63, tile=qq>>9, kt=tile&15, nt=tile>>4;
    int k=kt*32+((lane>>4)<<3)+j, n=nt*16+(lane&15);
    v = (n<64) ? paw1[((size_t)ly*512+k)*64+n] : piw1[((size_t)ly*512+k)*16+(n-64)];
  } else if (t < OFF_WF) {                            // [512][96] pbw flat (c=k*32+j), K32=16
    int q=(int)(t-OFF_WB); int ly=q/SZ_WB; int qq=q%SZ_WB;
    int j=qq&7, lane=(qq>>3)&63, tile=qq>>9, kt=tile&15, nt=tile>>4;
    int k=kt*32+((lane>>4)<<3)+j, c=nt*16+(lane&15);
    v = pbw[(((size_t)ly*3+(c>>5))*512+k)*32+(c&31)];
  } else if (t < OFF_WG) {                            // [96][512] pfw, K32=3
    int q=(int)(t-OFF_WF); int ly=q/SZ_WF; int qq=q%SZ_WF;
    int j=qq&7, lane=(qq>>3)&63, tile=qq>>9, kt=tile%3, nt=tile/3;
    int k=kt*32+((lane>>4)<<3)+j, n=nt*16+(lane&15);
    v = pfw[((size_t)ly*96+k)*512+n];
  } else if (t < OFF_WC) {                            // [512][512] pgw
    int q=(int)(t-OFF_WG); int ly=q/SZ_WG; int qq=q%SZ_WG;
    int j=qq&7, lane=(qq>>3)&63, tile=qq>>9, kt=tile&15, nt=tile>>4;
    int k=kt*32+((lane>>4)<<3)+j, n=nt*16+(lane&15);
    v = pgw[((size_t)ly*512+k)*512+n];
  } else if (t < OFF_WH) {                            // [512][512] fcw
    int q=(int)(t-OFF_WC); int ly=q/SZ_WC; int qq=q%SZ_WC;
    int j=qq&7, lane=(qq>>3)&63, tile=qq>>9, kt=tile&15, nt=tile>>4;
    int k=kt*32+((lane>>4)<<3)+j, n=nt*16+(lane&15);
    v = fcw[((size_t)ly*512+k)*512+n];
  } else if (t < OFF_WH2) {                           // [512][192] heads hidden
    int qq=(int)(t-OFF_WH);
    int j=qq&7, lane=(qq>>3)&63, tile=qq>>9, kt=tile&15, nt=tile>>4;
    int k=kt*32+((lane>>4)<<3)+j, n=nt*16+(lane&15);
    v = (n<64) ? nhw1[(size_t)k*64+n] : (n<128) ? dhw1[(size_t)k*64+(n-64)] : wtw1[(size_t)k*64+(n-128)];
  } else {                                            // [128][256] blockdiag(nhw2,dhw2), K32=4
    int qq=(int)(t-OFF_WH2);
    int j=qq&7, lane=(qq>>3)&63, tile=qq>>9, kt=tile&3, nt=tile>>2;
    int k=kt*32+((lane>>4)<<3)+j, n=nt*16+(lane&15);
    if (k<64) v = (n<128) ? nhw2[(size_t)k*128+n] : 0.f;
    else      v = (n>=128)? dhw2[(size_t)(k-64)*128+(n-128)] : 0.f;
  }
  ws[t] = f2b(v);
}

// ---------------- fused network ----------------
// 32 rows/block, 512 threads (8 waves), double-buffered h (hA/hB 32KB)
// + sU 8KB + sW 8KB = 80KB LDS. Register/occupancy map (R14-R18 measured):
//   alloc = 256/min_waves_per_eu; (512,2)->128: clean but 1 blk/CU (356+us);
//   (512,4)->64: 2 blk/CU but live~85 spills 150MB/side (431us).
// (512,3)->~85: granule ~88 -> 5 waves/SIMD -> 20 slots -> 2 blocks WITH
// slack (R15: exact 16/16 fit does not schedule), and 85 >= live state ->
// spill-free. Every phase writes results directly to hB/sW (no cross-barrier
// register state).
__global__ __launch_bounds__(512, 3) void pan_main(
  const float* __restrict__ x,
  const float* __restrict__ pbb,  const float* __restrict__ pab1,
  const float* __restrict__ paw2, const float* __restrict__ pab2,
  const float* __restrict__ pib1, const float* __restrict__ piw2,
  const float* __restrict__ pib2, const float* __restrict__ pfb,
  const float* __restrict__ pgb,  const float* __restrict__ fcb,
  const float* __restrict__ bng,  const float* __restrict__ bnb,
  const float* __restrict__ bnm,  const float* __restrict__ bnv,
  const float* __restrict__ nhb1, const float* __restrict__ nhb2,
  const float* __restrict__ dhb1, const float* __restrict__ dhb2,
  const float* __restrict__ wtb1, const float* __restrict__ wtw2,
  const float* __restrict__ wtb2,
  const short* __restrict__ ws, float* __restrict__ out)
{
  __shared__ __align__(16) char lds[81920];
  char* hA = lds;            // current h [32][512] bf16, stride 1024B, byte ^= (row&7)<<4
  char* hB = lds + 32768;    // next h (same layout); heads h1 [32][384B] goes here
  char* sU = lds + 65536;    // sT bf16 [32][80] @0 (5120) | ci f32 [32] @5120 | cwci bf16 [32][32] @5248
  char* sW = lds + 73728;    // weighted [32][128] bf16 swizzled, stride 256B

  const int tid  = threadIdx.x;
  const int wave = tid >> 6;
  const int l    = tid & 63;
  const int lr   = l & 15;
  const int lb   = l >> 4;
  const int swzA = (lr & 7) << 4;
  const size_t row0 = (size_t)blockIdx.x * 32;

  // ---- load x tile -> hA (bf16, swizzled)
  #pragma unroll 2
  for (int c = tid; c < 2048; c += 512) {
    int row = c >> 6, k0 = (c & 63) << 3;
    const float4* s0 = (const float4*)(x + (row0 + row)*512 + k0);
    float4 f0 = s0[0], f1 = s0[1];
    bf16x8 p;
    p[0]=f2b(f0.x); p[1]=f2b(f0.y); p[2]=f2b(f0.z); p[3]=f2b(f0.w);
    p[4]=f2b(f1.x); p[5]=f2b(f1.y); p[6]=f2b(f1.z); p[7]=f2b(f1.w);
    *(bf16x8*)(hA + row*1024 + ((k0*2) ^ ((row&7)<<4))) = p;
  }
  __syncthreads();

  auto ldA = [&](const char* base, int rt, int kt) -> bf16x8 {
    int row = rt*16 + lr;
    return *(const bf16x8*)(base + row*1024 + ((kt*64 + lb*16) ^ swzA));
  };
  auto ldB = [&](const short* W, int K32, int nt, int kt) -> bf16x8 {
    return *(const bf16x8*)(W + (((size_t)(nt*K32 + kt))*64 + l)*8);
  };
  auto ldH = [&](const char* base, int row, int col) -> float {
    return b2f(*(const short*)(base + row*1024 + ((col*2) ^ ((row&7)<<4))));
  };
  auto stH = [&](char* base, int row, int col, float v) {
    *(short*)(base + row*1024 + ((col*2) ^ ((row&7)<<4))) = f2b(v);
  };
  const f32x4 FZ = {0.f,0.f,0.f,0.f};

  // ================= PAN layers =================
  for (int ly = 0; ly < 3; ++ly) {
    // --- t_all = relu(h @ [paw1|piw1] + b) -> sT  (N=80: waves 0..4)
    if (wave < 5) {
      const short* W = ws + OFF_WT + (size_t)ly*SZ_WT;
      f32x4 acc[2];
      #pragma unroll
      for (int rt=0;rt<2;++rt) acc[rt] = FZ;
      #pragma unroll 2
      for (int kt=0;kt<16;++kt) {
        bf16x8 b = ldB(W,16,wave,kt);
        #pragma unroll
        for (int rt=0;rt<2;++rt) acc[rt] = MFMA(ldA(hA,rt,kt), b, acc[rt]);
      }
      const int col = wave*16 + lr;
      const float bias = (col<64) ? pab1[ly*64+col] : pib1[ly*16+(col-64)];
      #pragma unroll
      for (int rt=0;rt<2;++rt)
        #pragma unroll
        for (int jj=0;jj<4;++jj) {
          int row = rt*16 + lb*4 + jj;
          *(short*)(sU + row*160 + col*2) = f2b(fmaxf(acc[rt][jj]+bias, 0.f));
        }
    }
    __syncthreads();
    // --- ci = sigmoid(t2 @ piw2 + b)  (threads 0..31, vectorized reads)
    if (tid < 32) {
      float s = pib2[ly];
      bf16x8 t0 = *(const bf16x8*)(sU + tid*160 + 128);
      bf16x8 t1 = *(const bf16x8*)(sU + tid*160 + 144);
      #pragma unroll
      for (int i=0;i<8;++i) {
        s += b2f(t0[i]) * piw2[ly*16+i];
        s += b2f(t1[i]) * piw2[ly*16+8+i];
      }
      *(float*)(sU + 5120 + tid*4) = sigm(s);
    }
    __syncthreads();
    // --- cwci = sigmoid(t1 @ paw2 + b) * ci  (all 512 thr, 2 outputs/thread)
    {
      const int r = tid>>4, j0 = (tid&15)<<1;
      float a2[2];
      a2[0] = pab2[ly*32 + j0];
      a2[1] = pab2[ly*32 + j0 + 1];
      #pragma unroll 2
      for (int k8=0;k8<8;++k8) {
        bf16x8 tv8 = *(const bf16x8*)(sU + r*160 + k8*16);
        #pragma unroll
        for (int i8=0;i8<8;++i8) {
          float tv = b2f(tv8[i8]);
          float2 wr = *(const float2*)(paw2 + ((size_t)ly*64 + k8*8+i8)*32 + j0);
          a2[0]=fmaf(tv,wr.x,a2[0]); a2[1]=fmaf(tv,wr.y,a2[1]);
        }
      }
      const float civ = *(const float*)(sU + 5120 + r*4);
      *(short*)(sU + 5248 + (r*32 + j0    )*2) = f2b(sigm(a2[0]) * civ);
      *(short*)(sU + 5248 + (r*32 + j0 + 1)*2) = f2b(sigm(a2[1]) * civ);
    }
    __syncthreads();
    // --- feats = relu(h @ pbw + b); weighted -> sW DIRECTLY  (waves 0..5)
    if (wave < 6) {
      const short* W = ws + OFF_WB + (size_t)ly*SZ_WB;
      f32x4 acc[2];
      #pragma unroll
      for (int rt=0;rt<2;++rt) acc[rt] = FZ;
      #pragma unroll 2
      for (int kt=0;kt<16;++kt) {
        bf16x8 b = ldB(W,16,wave,kt);
        #pragma unroll
        for (int rt=0;rt<2;++rt) acc[rt] = MFMA(ldA(hA,rt,kt), b, acc[rt]);
      }
      const int col = wave*16 + lr;
      const float bias = pbb[ly*96 + col];
      #pragma unroll
      for (int rt=0;rt<2;++rt)
        #pragma unroll
        for (int jj=0;jj<4;++jj) {
          int row = rt*16 + lb*4 + jj;
          float cc = b2f(*(const short*)(sU + 5248 + (row*32 + (col&31))*2));
          float wv = fmaxf(acc[rt][jj]+bias, 0.f) * cc;
          *(short*)(sW + row*256 + ((col*2) ^ ((row&7)<<4))) = f2b(wv);
        }
    }
    __syncthreads();
    // --- gate = sigmoid(h @ pgw + b); h' = weighted @ pfw + pfb + gate*h -> hB DIRECTLY
    {
      const short* Wg = ws + OFF_WG + (size_t)ly*SZ_WG;
      const short* Wf = ws + OFF_WF + (size_t)ly*SZ_WF;
      #pragma unroll
      for (int p=0; p<2; ++p) {
        f32x4 acc[2][2];
        #pragma unroll
        for (int rt=0;rt<2;++rt) { acc[rt][0]=FZ; acc[rt][1]=FZ; }
        #pragma unroll 2
        for (int kt=0;kt<16;++kt) {
          bf16x8 b0 = ldB(Wg,16, wave*4+p*2+0, kt);
          bf16x8 b1 = ldB(Wg,16, wave*4+p*2+1, kt);
          #pragma unroll
          for (int rt=0;rt<2;++rt) {
            bf16x8 a = ldA(hA,rt,kt);
            acc[rt][0] = MFMA(a,b0,acc[rt][0]);
            acc[rt][1] = MFMA(a,b1,acc[rt][1]);
          }
        }
        #pragma unroll
        for (int c2=0;c2<2;++c2) {
          const int col = (wave*4+p*2+c2)*16 + lr;
          const float gb = pgb[ly*512+col];
          const float fb = pfb[ly*512+col];
          #pragma unroll
          for (int rt=0;rt<2;++rt)
            #pragma unroll
            for (int jj=0;jj<4;++jj) {
              int row = rt*16 + lb*4 + jj;
              acc[rt][c2][jj] = sigm(acc[rt][c2][jj]+gb)*ldH(hA,row,col) + fb;
            }
        }
        #pragma unroll 1
        for (int kt=0;kt<3;++kt) {   // fused accumulate, K=96, A from sW
          bf16x8 b0 = ldB(Wf,3, wave*4+p*2+0, kt);
          bf16x8 b1 = ldB(Wf,3, wave*4+p*2+1, kt);
          #pragma unroll
          for (int rt=0;rt<2;++rt) {
            int row = rt*16 + lr;
            bf16x8 a = *(const bf16x8*)(sW + row*256 + ((kt*64 + lb*16) ^ swzA));
            acc[rt][0] = MFMA(a,b0,acc[rt][0]);
            acc[rt][1] = MFMA(a,b1,acc[rt][1]);
          }
        }
        #pragma unroll
        for (int c2=0;c2<2;++c2) {
          const int col = (wave*4+p*2+c2)*16 + lr;
          #pragma unroll
          for (int rt=0;rt<2;++rt)
            #pragma unroll
            for (int jj=0;jj<4;++jj)
              stH(hB, rt*16 + lb*4 + jj, col, acc[rt][c2][jj]);
        }
      }
    }
    __syncthreads();
    { char* t = hA; hA = hB; hB = t; }
  }

  // ================= FC + BN(eval) + ReLU  x3 =================
  for (int fi=0; fi<3; ++fi) {
    const short* W = ws + OFF_WC + (size_t)fi*SZ_WC;
    #pragma unroll
    for (int p=0; p<2; ++p) {
      f32x4 acc[2][2];
      #pragma unroll
      for (int rt=0;rt<2;++rt) { acc[rt][0]=FZ; acc[rt][1]=FZ; }
      #pragma unroll 2
      for (int kt=0;kt<16;++kt) {
        bf16x8 b0 = ldB(W,16, wave*4+p*2+0, kt);
        bf16x8 b1 = ldB(W,16, wave*4+p*2+1, kt);
        #pragma unroll
        for (int rt=0;rt<2;++rt) {
          bf16x8 a = ldA(hA,rt,kt);
          acc[rt][0] = MFMA(a,b0,acc[rt][0]);
          acc[rt][1] = MFMA(a,b1,acc[rt][1]);
        }
      }
      #pragma unroll
      for (int c2=0;c2<2;++c2) {
        const int col = (wave*4+p*2+c2)*16 + lr;
        const float sc = bng[fi*512+col] * rsqrtf(bnv[fi*512+col] + 1e-5f);
        const float of = bnb[fi*512+col] - bnm[fi*512+col]*sc;
        const float bb = fcb[fi*512+col];
        #pragma unroll
        for (int rt=0;rt<2;++rt)
          #pragma unroll
          for (int jj=0;jj<4;++jj)
            stH(hB, rt*16 + lb*4 + jj, col,
                fmaxf((acc[rt][c2][jj] + bb)*sc + of, 0.f));
      }
    }
    __syncthreads();
    { char* t = hA; hA = hB; hB = t; }
  }

  // ================= heads =================
  // h1 = relu(h @ [nhw1|dhw1|wtw1] + b): N=192 = 12 tiles; wave does tile
  // `wave`, and (wave<4) tile 8+wave. Written DIRECTLY to hB, stride 384.
  {
    const short* W = ws + OFF_WH;
    {
      f32x4 acc[2];
      #pragma unroll
      for (int rt=0;rt<2;++rt) acc[rt] = FZ;
      #pragma unroll 2
      for (int kt=0;kt<16;++kt) {
        bf16x8 b = ldB(W,16,wave,kt);
        #pragma unroll
        for (int rt=0;rt<2;++rt) acc[rt] = MFMA(ldA(hA,rt,kt), b, acc[rt]);
      }
      const int col = wave*16 + lr;
      const float bias = (col<64) ? nhb1[col] : dhb1[col-64];
      #pragma unroll
      for (int rt=0;rt<2;++rt)
        #pragma unroll
        for (int jj=0;jj<4;++jj) {
          int row = rt*16 + lb*4 + jj;
          *(short*)(hB + row*384 + ((col*2) ^ ((row&7)<<4))) =
              f2b(fmaxf(acc[rt][jj]+bias, 0.f));
        }
    }
    if (wave < 4) {
      f32x4 acc[2];
      #pragma unroll
      for (int rt=0;rt<2;++rt) acc[rt] = FZ;
      #pragma unroll 2
      for (int kt=0;kt<16;++kt) {
        bf16x8 b = ldB(W,16, 8+wave, kt);
        #pragma unroll
        for (int rt=0;rt<2;++rt) acc[rt] = MFMA(ldA(hA,rt,kt), b, acc[rt]);
      }
      const int col = (8+wave)*16 + lr;   // 128..191 -> wait-head hidden
      const float bias = wtb1[col-128];
      #pragma unroll
      for (int rt=0;rt<2;++rt)
        #pragma unroll
        for (int jj=0;jj<4;++jj) {
          int row = rt*16 + lb*4 + jj;
          *(short*)(hB + row*384 + ((col*2) ^ ((row&7)<<4))) =
              f2b(fmaxf(acc[rt][jj]+bias, 0.f));
        }
    }
  }
  __syncthreads();
  { // logits = h1[:, :128] @ blockdiag(nhw2,dhw2): 16 tiles = 8 waves x 2
    const short* W2 = ws + OFF_WH2;
    #pragma unroll
    for (int p=0;p<2;++p) {
      f32x4 acc[2];
      #pragma unroll
      for (int rt=0;rt<2;++rt) acc[rt] = FZ;
      #pragma unroll 2
      for (int kt=0;kt<4;++kt) {
        bf16x8 b = ldB(W2,4, wave*2+p, kt);
        #pragma unroll
        for (int rt=0;rt<2;++rt) {
          int row = rt*16 + lr;
          bf16x8 a = *(const bf16x8*)(hB + row*384 + ((kt*64 + lb*16) ^ swzA));
          acc[rt] = MFMA(a,b,acc[rt]);
        }
      }
      const int col2 = (wave*2+p)*16 + lr;
      const bool isn = col2 < 128;
      const int cc = col2 & 127;
      const float bias = isn ? nhb2[cc] : dhb2[cc];
      const size_t obase = isn ? (size_t)0 : (size_t)4194304;
      #pragma unroll
      for (int rt=0;rt<2;++rt)
        #pragma unroll
        for (int jj=0;jj<4;++jj) {
          int row = rt*16 + lb*4 + jj;
          size_t rg = row0 + row;
          float2 caps = *(const float2*)(x + rg*512 + 508);   // (s_nurse_max, s_doctor_max)
          int cap = (int)(isn ? caps.x : caps.y);
          float v = acc[rt][jj] + bias;
          out[obase + rg*128 + cc] = (cc <= cap) ? v : -1e9f;
        }
    }
  }
  // wait_time = h1[:, 128:192] @ wtw2 + b (read-only on h1)
  if (tid < 32) {
    float s = wtb2[0];
    #pragma unroll 2
    for (int k8=0;k8<8;++k8) {
      bf16x8 hv = *(const bf16x8*)(hB + tid*384 + ((256 + k8*16) ^ ((tid&7)<<4)));
      #pragma unroll
      for (int i=0;i<8;++i) s += b2f(hv[i]) * wtw2[k8*8+i];
    }
    out[(size_t)8388608 + row0 + tid] = s;
  }
}

extern "C" void kernel_launch(void* const* d_in, const int* in_sizes, int n_in,
                              void* d_out, int out_size, void* d_ws, size_t ws_size,
                              hipStream_t stream) {
  const float* x    = (const float*)d_in[0];
  const float* pbw  = (const float*)d_in[1];
  const float* pbb  = (const float*)d_in[2];
  const float* paw1 = (const float*)d_in[3];
  const float* pab1 = (const float*)d_in[4];
  const float* paw2 = (const float*)d_in[5];
  const float* pab2 = (const float*)d_in[6];
  const float* piw1 = (const float*)d_in[7];
  const float* pib1 = (const float*)d_in[8];
  const float* piw2 = (const float*)d_in[9];
  const float* pib2 = (const float*)d_in[10];
  const float* pfw  = (const float*)d_in[11];
  const float* pfb  = (const float*)d_in[12];
  const float* pgw  = (const float*)d_in[13];
  const float* pgb  = (const float*)d_in[14];
  const float* fcw  = (const float*)d_in[15];
  const float* fcb  = (const float*)d_in[16];
  const float* bng  = (const float*)d_in[17];
  const float* bnb  = (const float*)d_in[18];
  const float* bnm  = (const float*)d_in[19];
  const float* bnv  = (const float*)d_in[20];
  const float* nhw1 = (const float*)d_in[21];
  const float* nhb1 = (const float*)d_in[22];
  const float* nhw2 = (const float*)d_in[23];
  const float* nhb2 = (const float*)d_in[24];
  const float* dhw1 = (const float*)d_in[25];
  const float* dhb1 = (const float*)d_in[26];
  const float* dhw2 = (const float*)d_in[27];
  const float* dhb2 = (const float*)d_in[28];
  const float* wtw1 = (const float*)d_in[29];
  const float* wtb1 = (const float*)d_in[30];
  const float* wtw2 = (const float*)d_in[31];
  const float* wtb2 = (const float*)d_in[32];
  short* ws  = (short*)d_ws;
  float* out = (float*)d_out;

  prep_weights<<<(int)((WS_TOTAL + 255)/256), 256, 0, stream>>>(
      pbw, paw1, piw1, pfw, pgw, fcw, nhw1, nhw2, dhw1, dhw2, wtw1, ws);
  pan_main<<<1024, 512, 0, stream>>>(
      x, pbb, pab1, paw2, pab2, pib1, piw2, pib2, pfb, pgb, fcb,
      bng, bnb, bnm, bnv, nhb1, nhb2, dhb1, dhb2, wtb1, wtw2, wtb2, ws, out);
}

// Round 20
// 382.778 us; speedup vs baseline: 1.6663x; 1.6663x over previous
//
#include <hip/hip_runtime.h>

#define DI __device__ __forceinline__

typedef short bf16x8 __attribute__((ext_vector_type(8)));
typedef float f32x4  __attribute__((ext_vector_type(4)));

#define MFMA(a,b,c) __builtin_amdgcn_mfma_f32_16x16x32_bf16(a,b,c,0,0,0)

constexpr int    SZ_WT = 512*80;
constexpr int    SZ_WB = 512*96;
constexpr int    SZ_WF = 96*512;
constexpr int    SZ_WG = 512*512;
constexpr int    SZ_WC = 512*512;
constexpr size_t OFF_WT  = 0;
constexpr size_t OFF_WB  = OFF_WT + 3*(size_t)SZ_WT;     // 122880
constexpr size_t OFF_WF  = OFF_WB + 3*(size_t)SZ_WB;     // 270336
constexpr size_t OFF_WG  = OFF_WF + 3*(size_t)SZ_WF;     // 417792
constexpr size_t OFF_WC  = OFF_WG + 3*(size_t)SZ_WG;     // 1204224
constexpr size_t OFF_WH  = OFF_WC + 3*(size_t)SZ_WC;     // 1990656  [512][192] nhw1|dhw1|wtw1
constexpr size_t OFF_WH2 = OFF_WH + (size_t)512*192;     // 2088960  [128][256] blockdiag(nhw2,dhw2)
constexpr size_t WS_TOTAL= OFF_WH2 + (size_t)128*256;    // 2121728 bf16 elems

DI short f2b(float f){ unsigned u; __builtin_memcpy(&u,&f,4); u += 0x7fffu + ((u>>16)&1u); return (short)(u>>16); }
DI float b2f(short s){ unsigned u = ((unsigned)(unsigned short)s)<<16; float f; __builtin_memcpy(&f,&u,4); return f; }
DI float sigm(float x){ return 1.f/(1.f+__expf(-x)); }

// ---------------- weight prepass: fp32 -> bf16 MFMA-B-fragment layout ----------------
// frag element t = ((nt*K32 + kt)*64 + lane)*8 + j  <->  W[kt*32 + (lane>>4)*8 + j][nt*16 + (lane&15)]
__global__ __launch_bounds__(256) void prep_weights(
    const float* __restrict__ pbw,  const float* __restrict__ paw1,
    const float* __restrict__ piw1, const float* __restrict__ pfw,
    const float* __restrict__ pgw,  const float* __restrict__ fcw,
    const float* __restrict__ nhw1, const float* __restrict__ nhw2,
    const float* __restrict__ dhw1, const float* __restrict__ dhw2,
    const float* __restrict__ wtw1, short* __restrict__ ws)
{
  size_t t = (size_t)blockIdx.x*256 + threadIdx.x;
  if (t >= WS_TOTAL) return;
  float v = 0.f;
  if (t < OFF_WB) {                                   // [512][80] = paw1 | piw1, K32=16
    int q=(int)t; int ly=q/SZ_WT; int qq=q%SZ_WT;
    int j=qq&7, lane=(qq>>3)&63, tile=qq>>9, kt=tile&15, nt=tile>>4;
    int k=kt*32+((lane>>4)<<3)+j, n=nt*16+(lane&15);
    v = (n<64) ? paw1[((size_t)ly*512+k)*64+n] : piw1[((size_t)ly*512+k)*16+(n-64)];
  } else if (t < OFF_WF) {                            // [512][96] pbw flat (c=k*32+j), K32=16
    int q=(int)(t-OFF_WB); int ly=q/SZ_WB; int qq=q%SZ_WB;
    int j=qq&7, lane=(qq>>3)&63, tile=qq>>9, kt=tile&15, nt=tile>>4;
    int k=kt*32+((lane>>4)<<3)+j, c=nt*16+(lane&15);
    v = pbw[(((size_t)ly*3+(c>>5))*512+k)*32+(c&31)];
  } else if (t < OFF_WG) {                            // [96][512] pfw, K32=3
    int q=(int)(t-OFF_WF); int ly=q/SZ_WF; int qq=q%SZ_WF;
    int j=qq&7, lane=(qq>>3)&63, tile=qq>>9, kt=tile%3, nt=tile/3;
    int k=kt*32+((lane>>4)<<3)+j, n=nt*16+(lane&15);
    v = pfw[((size_t)ly*96+k)*512+n];
  } else if (t < OFF_WC) {                            // [512][512] pgw
    int q=(int)(t-OFF_WG); int ly=q/SZ_WG; int qq=q%SZ_WG;
    int j=qq&7, lane=(qq>>3)&63, tile=qq>>9, kt=tile&15, nt=tile>>4;
    int k=kt*32+((lane>>4)<<3)+j, n=nt*16+(lane&15);
    v = pgw[((size_t)ly*512+k)*512+n];
  } else if (t < OFF_WH) {                            // [512][512] fcw
    int q=(int)(t-OFF_WC); int ly=q/SZ_WC; int qq=q%SZ_WC;
    int j=qq&7, lane=(qq>>3)&63, tile=qq>>9, kt=tile&15, nt=tile>>4;
    int k=kt*32+((lane>>4)<<3)+j, n=nt*16+(lane&15);
    v = fcw[((size_t)ly*512+k)*512+n];
  } else if (t < OFF_WH2) {                           // [512][192] heads hidden
    int qq=(int)(t-OFF_WH);
    int j=qq&7, lane=(qq>>3)&63, tile=qq>>9, kt=tile&15, nt=tile>>4;
    int k=kt*32+((lane>>4)<<3)+j, n=nt*16+(lane&15);
    v = (n<64) ? nhw1[(size_t)k*64+n] : (n<128) ? dhw1[(size_t)k*64+(n-64)] : wtw1[(size_t)k*64+(n-128)];
  } else {                                            // [128][256] blockdiag(nhw2,dhw2), K32=4
    int qq=(int)(t-OFF_WH2);
    int j=qq&7, lane=(qq>>3)&63, tile=qq>>9, kt=tile&3, nt=tile>>2;
    int k=kt*32+((lane>>4)<<3)+j, n=nt*16+(lane&15);
    if (k<64) v = (n<128) ? nhw2[(size_t)k*128+n] : 0.f;
    else      v = (n>=128)? dhw2[(size_t)(k-64)*128+(n-128)] : 0.f;
  }
  ws[t] = f2b(v);
}

// ---------------- fused network ----------------
// 32 rows/block, 512 threads (8 waves), double-buffered h (hA/hB 32KB)
// + sU 8KB + sW 8KB = 80KB LDS. Occupancy map (R8-R19 measured): 2 blocks/CU
// requires VGPR<=64 (84 and up -> 1 block). launch_bounds(512,4) -> 64-reg
// alloc. To fit 64 SPILL-FREE, the 512-col phases (gate, FC) run as FOUR
// single-column passes: acc[2]=8 regs, one B-frag stream; peak live ~40.
// All results written directly to hB/sW (zero cross-barrier register state).
__global__ __launch_bounds__(512, 4) void pan_main(
  const float* __restrict__ x,
  const float* __restrict__ pbb,  const float* __restrict__ pab1,
  const float* __restrict__ paw2, const float* __restrict__ pab2,
  const float* __restrict__ pib1, const float* __restrict__ piw2,
  const float* __restrict__ pib2, const float* __restrict__ pfb,
  const float* __restrict__ pgb,  const float* __restrict__ fcb,
  const float* __restrict__ bng,  const float* __restrict__ bnb,
  const float* __restrict__ bnm,  const float* __restrict__ bnv,
  const float* __restrict__ nhb1, const float* __restrict__ nhb2,
  const float* __restrict__ dhb1, const float* __restrict__ dhb2,
  const float* __restrict__ wtb1, const float* __restrict__ wtw2,
  const float* __restrict__ wtb2,
  const short* __restrict__ ws, float* __restrict__ out)
{
  __shared__ __align__(16) char lds[81920];
  char* hA = lds;            // current h [32][512] bf16, stride 1024B, byte ^= (row&7)<<4
  char* hB = lds + 32768;    // next h (same layout); heads h1 [32][384B] goes here
  char* sU = lds + 65536;    // sT bf16 [32][80] @0 (5120) | ci f32 [32] @5120 | cwci bf16 [32][32] @5248
  char* sW = lds + 73728;    // weighted [32][128] bf16 swizzled, stride 256B

  const int tid  = threadIdx.x;
  const int wave = tid >> 6;
  const int l    = tid & 63;
  const int lr   = l & 15;
  const int lb   = l >> 4;
  const int swzA = (lr & 7) << 4;
  const size_t row0 = (size_t)blockIdx.x * 32;

  // ---- load x tile -> hA (bf16, swizzled)
  #pragma unroll 2
  for (int c = tid; c < 2048; c += 512) {
    int row = c >> 6, k0 = (c & 63) << 3;
    const float4* s0 = (const float4*)(x + (row0 + row)*512 + k0);
    float4 f0 = s0[0], f1 = s0[1];
    bf16x8 p;
    p[0]=f2b(f0.x); p[1]=f2b(f0.y); p[2]=f2b(f0.z); p[3]=f2b(f0.w);
    p[4]=f2b(f1.x); p[5]=f2b(f1.y); p[6]=f2b(f1.z); p[7]=f2b(f1.w);
    *(bf16x8*)(hA + row*1024 + ((k0*2) ^ ((row&7)<<4))) = p;
  }
  __syncthreads();

  auto ldA = [&](const char* base, int rt, int kt) -> bf16x8 {
    int row = rt*16 + lr;
    return *(const bf16x8*)(base + row*1024 + ((kt*64 + lb*16) ^ swzA));
  };
  auto ldB = [&](const short* W, int K32, int nt, int kt) -> bf16x8 {
    return *(const bf16x8*)(W + (((size_t)(nt*K32 + kt))*64 + l)*8);
  };
  auto ldH = [&](const char* base, int row, int col) -> float {
    return b2f(*(const short*)(base + row*1024 + ((col*2) ^ ((row&7)<<4))));
  };
  auto stH = [&](char* base, int row, int col, float v) {
    *(short*)(base + row*1024 + ((col*2) ^ ((row&7)<<4))) = f2b(v);
  };
  const f32x4 FZ = {0.f,0.f,0.f,0.f};

  // ================= PAN layers =================
  for (int ly = 0; ly < 3; ++ly) {
    // --- t_all = relu(h @ [paw1|piw1] + b) -> sT  (N=80: waves 0..4)
    if (wave < 5) {
      const short* W = ws + OFF_WT + (size_t)ly*SZ_WT;
      f32x4 acc[2];
      #pragma unroll
      for (int rt=0;rt<2;++rt) acc[rt] = FZ;
      #pragma unroll 2
      for (int kt=0;kt<16;++kt) {
        bf16x8 b = ldB(W,16,wave,kt);
        #pragma unroll
        for (int rt=0;rt<2;++rt) acc[rt] = MFMA(ldA(hA,rt,kt), b, acc[rt]);
      }
      const int col = wave*16 + lr;
      const float bias = (col<64) ? pab1[ly*64+col] : pib1[ly*16+(col-64)];
      #pragma unroll
      for (int rt=0;rt<2;++rt)
        #pragma unroll
        for (int jj=0;jj<4;++jj) {
          int row = rt*16 + lb*4 + jj;
          *(short*)(sU + row*160 + col*2) = f2b(fmaxf(acc[rt][jj]+bias, 0.f));
        }
    }
    __syncthreads();
    // --- ci = sigmoid(t2 @ piw2 + b)  (threads 0..31, vectorized reads)
    if (tid < 32) {
      float s = pib2[ly];
      bf16x8 t0 = *(const bf16x8*)(sU + tid*160 + 128);
      bf16x8 t1 = *(const bf16x8*)(sU + tid*160 + 144);
      #pragma unroll
      for (int i=0;i<8;++i) {
        s += b2f(t0[i]) * piw2[ly*16+i];
        s += b2f(t1[i]) * piw2[ly*16+8+i];
      }
      *(float*)(sU + 5120 + tid*4) = sigm(s);
    }
    __syncthreads();
    // --- cwci = sigmoid(t1 @ paw2 + b) * ci  (all 512 thr, 2 outputs/thread)
    {
      const int r = tid>>4, j0 = (tid&15)<<1;
      float a2[2];
      a2[0] = pab2[ly*32 + j0];
      a2[1] = pab2[ly*32 + j0 + 1];
      #pragma unroll 2
      for (int k8=0;k8<8;++k8) {
        bf16x8 tv8 = *(const bf16x8*)(sU + r*160 + k8*16);
        #pragma unroll
        for (int i8=0;i8<8;++i8) {
          float tv = b2f(tv8[i8]);
          float2 wr = *(const float2*)(paw2 + ((size_t)ly*64 + k8*8+i8)*32 + j0);
          a2[0]=fmaf(tv,wr.x,a2[0]); a2[1]=fmaf(tv,wr.y,a2[1]);
        }
      }
      const float civ = *(const float*)(sU + 5120 + r*4);
      *(short*)(sU + 5248 + (r*32 + j0    )*2) = f2b(sigm(a2[0]) * civ);
      *(short*)(sU + 5248 + (r*32 + j0 + 1)*2) = f2b(sigm(a2[1]) * civ);
    }
    __syncthreads();
    // --- feats = relu(h @ pbw + b); weighted -> sW DIRECTLY  (waves 0..5)
    if (wave < 6) {
      const short* W = ws + OFF_WB + (size_t)ly*SZ_WB;
      f32x4 acc[2];
      #pragma unroll
      for (int rt=0;rt<2;++rt) acc[rt] = FZ;
      #pragma unroll 2
      for (int kt=0;kt<16;++kt) {
        bf16x8 b = ldB(W,16,wave,kt);
        #pragma unroll
        for (int rt=0;rt<2;++rt) acc[rt] = MFMA(ldA(hA,rt,kt), b, acc[rt]);
      }
      const int col = wave*16 + lr;
      const float bias = pbb[ly*96 + col];
      #pragma unroll
      for (int rt=0;rt<2;++rt)
        #pragma unroll
        for (int jj=0;jj<4;++jj) {
          int row = rt*16 + lb*4 + jj;
          float cc = b2f(*(const short*)(sU + 5248 + (row*32 + (col&31))*2));
          float wv = fmaxf(acc[rt][jj]+bias, 0.f) * cc;
          *(short*)(sW + row*256 + ((col*2) ^ ((row&7)<<4))) = f2b(wv);
        }
    }
    __syncthreads();
    // --- gate = sigmoid(h @ pgw + b); h' = weighted @ pfw + pfb + gate*h
    //     FOUR single-col passes (acc[2]=8 regs) -> hB DIRECTLY (no WAR: hB!=hA).
    {
      const short* Wg = ws + OFF_WG + (size_t)ly*SZ_WG;
      const short* Wf = ws + OFF_WF + (size_t)ly*SZ_WF;
      #pragma unroll 1
      for (int c=0; c<4; ++c) {
        f32x4 acc[2];
        #pragma unroll
        for (int rt=0;rt<2;++rt) acc[rt] = FZ;
        #pragma unroll 2
        for (int kt=0;kt<16;++kt) {
          bf16x8 b = ldB(Wg,16, wave*4+c, kt);
          #pragma unroll
          for (int rt=0;rt<2;++rt) acc[rt] = MFMA(ldA(hA,rt,kt), b, acc[rt]);
        }
        const int col = (wave*4+c)*16 + lr;
        const float gb = pgb[ly*512+col];
        const float fb = pfb[ly*512+col];
        #pragma unroll
        for (int rt=0;rt<2;++rt)
          #pragma unroll
          for (int jj=0;jj<4;++jj) {
            int row = rt*16 + lb*4 + jj;
            acc[rt][jj] = sigm(acc[rt][jj]+gb)*ldH(hA,row,col) + fb;
          }
        #pragma unroll 1
        for (int kt=0;kt<3;++kt) {   // fused accumulate, K=96, A from sW
          bf16x8 b = ldB(Wf,3, wave*4+c, kt);
          #pragma unroll
          for (int rt=0;rt<2;++rt) {
            int row = rt*16 + lr;
            bf16x8 a = *(const bf16x8*)(sW + row*256 + ((kt*64 + lb*16) ^ swzA));
            acc[rt] = MFMA(a,b,acc[rt]);
          }
        }
        #pragma unroll
        for (int rt=0;rt<2;++rt)
          #pragma unroll
          for (int jj=0;jj<4;++jj)
            stH(hB, rt*16 + lb*4 + jj, col, acc[rt][jj]);
      }
    }
    __syncthreads();
    { char* t = hA; hA = hB; hB = t; }
  }

  // ================= FC + BN(eval) + ReLU  x3 =================
  for (int fi=0; fi<3; ++fi) {
    const short* W = ws + OFF_WC + (size_t)fi*SZ_WC;
    #pragma unroll 1
    for (int c=0; c<4; ++c) {
      f32x4 acc[2];
      #pragma unroll
      for (int rt=0;rt<2;++rt) acc[rt] = FZ;
      #pragma unroll 2
      for (int kt=0;kt<16;++kt) {
        bf16x8 b = ldB(W,16, wave*4+c, kt);
        #pragma unroll
        for (int rt=0;rt<2;++rt) acc[rt] = MFMA(ldA(hA,rt,kt), b, acc[rt]);
      }
      const int col = (wave*4+c)*16 + lr;
      const float sc = bng[fi*512+col] * rsqrtf(bnv[fi*512+col] + 1e-5f);
      const float of = bnb[fi*512+col] - bnm[fi*512+col]*sc;
      const float bb = fcb[fi*512+col];
      #pragma unroll
      for (int rt=0;rt<2;++rt)
        #pragma unroll
        for (int jj=0;jj<4;++jj)
          stH(hB, rt*16 + lb*4 + jj, col,
              fmaxf((acc[rt][jj] + bb)*sc + of, 0.f));
    }
    __syncthreads();
    { char* t = hA; hA = hB; hB = t; }
  }

  // ================= heads =================
  // h1 = relu(h @ [nhw1|dhw1|wtw1] + b): N=192 = 12 tiles; wave does tile
  // `wave`, and (wave<4) tile 8+wave. Written DIRECTLY to hB, stride 384.
  {
    const short* W = ws + OFF_WH;
    {
      f32x4 acc[2];
      #pragma unroll
      for (int rt=0;rt<2;++rt) acc[rt] = FZ;
      #pragma unroll 2
      for (int kt=0;kt<16;++kt) {
        bf16x8 b = ldB(W,16,wave,kt);
        #pragma unroll
        for (int rt=0;rt<2;++rt) acc[rt] = MFMA(ldA(hA,rt,kt), b, acc[rt]);
      }
      const int col = wave*16 + lr;
      const float bias = (col<64) ? nhb1[col] : dhb1[col-64];
      #pragma unroll
      for (int rt=0;rt<2;++rt)
        #pragma unroll
        for (int jj=0;jj<4;++jj) {
          int row = rt*16 + lb*4 + jj;
          *(short*)(hB + row*384 + ((col*2) ^ ((row&7)<<4))) =
              f2b(fmaxf(acc[rt][jj]+bias, 0.f));
        }
    }
    if (wave < 4) {
      f32x4 acc[2];
      #pragma unroll
      for (int rt=0;rt<2;++rt) acc[rt] = FZ;
      #pragma unroll 2
      for (int kt=0;kt<16;++kt) {
        bf16x8 b = ldB(W,16, 8+wave, kt);
        #pragma unroll
        for (int rt=0;rt<2;++rt) acc[rt] = MFMA(ldA(hA,rt,kt), b, acc[rt]);
      }
      const int col = (8+wave)*16 + lr;   // 128..191 -> wait-head hidden
      const float bias = wtb1[col-128];
      #pragma unroll
      for (int rt=0;rt<2;++rt)
        #pragma unroll
        for (int jj=0;jj<4;++jj) {
          int row = rt*16 + lb*4 + jj;
          *(short*)(hB + row*384 + ((col*2) ^ ((row&7)<<4))) =
              f2b(fmaxf(acc[rt][jj]+bias, 0.f));
        }
    }
  }
  __syncthreads();
  { // logits = h1[:, :128] @ blockdiag(nhw2,dhw2): 16 tiles = 8 waves x 2
    const short* W2 = ws + OFF_WH2;
    #pragma unroll 1
    for (int p=0;p<2;++p) {
      f32x4 acc[2];
      #pragma unroll
      for (int rt=0;rt<2;++rt) acc[rt] = FZ;
      #pragma unroll 2
      for (int kt=0;kt<4;++kt) {
        bf16x8 b = ldB(W2,4, wave*2+p, kt);
        #pragma unroll
        for (int rt=0;rt<2;++rt) {
          int row = rt*16 + lr;
          bf16x8 a = *(const bf16x8*)(hB + row*384 + ((kt*64 + lb*16) ^ swzA));
          acc[rt] = MFMA(a,b,acc[rt]);
        }
      }
      const int col2 = (wave*2+p)*16 + lr;
      const bool isn = col2 < 128;
      const int cc = col2 & 127;
      const float bias = isn ? nhb2[cc] : dhb2[cc];
      const size_t obase = isn ? (size_t)0 : (size_t)4194304;
      #pragma unroll
      for (int rt=0;rt<2;++rt)
        #pragma unroll
        for (int jj=0;jj<4;++jj) {
          int row = rt*16 + lb*4 + jj;
          size_t rg = row0 + row;
          float2 caps = *(const float2*)(x + rg*512 + 508);   // (s_nurse_max, s_doctor_max)
          int cap = (int)(isn ? caps.x : caps.y);
          float v = acc[rt][jj] + bias;
          out[obase + rg*128 + cc] = (cc <= cap) ? v : -1e9f;
        }
    }
  }
  // wait_time = h1[:, 128:192] @ wtw2 + b (read-only on h1)
  if (tid < 32) {
    float s = wtb2[0];
    #pragma unroll 2
    for (int k8=0;k8<8;++k8) {
      bf16x8 hv = *(const bf16x8*)(hB + tid*384 + ((256 + k8*16) ^ ((tid&7)<<4)));
      #pragma unroll
      for (int i=0;i<8;++i) s += b2f(hv[i]) * wtw2[k8*8+i];
    }
    out[(size_t)8388608 + row0 + tid] = s;
  }
}

extern "C" void kernel_launch(void* const* d_in, const int* in_sizes, int n_in,
                              void* d_out, int out_size, void* d_ws, size_t ws_size,
                              hipStream_t stream) {
  const float* x    = (const float*)d_in[0];
  const float* pbw  = (const float*)d_in[1];
  const float* pbb  = (const float*)d_in[2];
  const float* paw1 = (const float*)d_in[3];
  const float* pab1 = (const float*)d_in[4];
  const float* paw2 = (const float*)d_in[5];
  const float* pab2 = (const float*)d_in[6];
  const float* piw1 = (const float*)d_in[7];
  const float* pib1 = (const float*)d_in[8];
  const float* piw2 = (const float*)d_in[9];
  const float* pib2 = (const float*)d_in[10];
  const float* pfw  = (const float*)d_in[11];
  const float* pfb  = (const float*)d_in[12];
  const float* pgw  = (const float*)d_in[13];
  const float* pgb  = (const float*)d_in[14];
  const float* fcw  = (const float*)d_in[15];
  const float* fcb  = (const float*)d_in[16];
  const float* bng  = (const float*)d_in[17];
  const float* bnb  = (const float*)d_in[18];
  const float* bnm  = (const float*)d_in[19];
  const float* bnv  = (const float*)d_in[20];
  const float* nhw1 = (const float*)d_in[21];
  const float* nhb1 = (const float*)d_in[22];
  const float* nhw2 = (const float*)d_in[23];
  const float* nhb2 = (const float*)d_in[24];
  const float* dhw1 = (const float*)d_in[25];
  const float* dhb1 = (const float*)d_in[26];
  const float* dhw2 = (const float*)d_in[27];
  const float* dhb2 = (const float*)d_in[28];
  const float* wtw1 = (const float*)d_in[29];
  const float* wtb1 = (const float*)d_in[30];
  const float* wtw2 = (const float*)d_in[31];
  const float* wtb2 = (const float*)d_in[32];
  short* ws  = (short*)d_ws;
  float* out = (float*)d_out;

  prep_weights<<<(int)((WS_TOTAL + 255)/256), 256, 0, stream>>>(
      pbw, paw1, piw1, pfw, pgw, fcw, nhw1, nhw2, dhw1, dhw2, wtw1, ws);
  pan_main<<<1024, 512, 0, stream>>>(
      x, pbb, pab1, paw2, pab2, pib1, piw2, pib2, pfb, pgb, fcb,
      bng, bnb, bnm, bnv, nhb1, nhb2, dhb1, dhb2, wtb1, wtw2, wtb2, ws, out);
}

// Round 21
// 329.389 us; speedup vs baseline: 1.9364x; 1.1621x over previous
//
#include <hip/hip_runtime.h>

#define DI __device__ __forceinline__

typedef short bf16x8 __attribute__((ext_vector_type(8)));
typedef float f32x4  __attribute__((ext_vector_type(4)));

#define MFMA(a,b,c) __builtin_amdgcn_mfma_f32_16x16x32_bf16(a,b,c,0,0,0)

constexpr int    SZ_WT = 512*80;
constexpr int    SZ_WB = 512*96;
constexpr int    SZ_WF = 96*512;
constexpr int    SZ_WG = 512*512;
constexpr int    SZ_WC = 512*512;
constexpr size_t OFF_WT  = 0;
constexpr size_t OFF_WB  = OFF_WT + 3*(size_t)SZ_WT;     // 122880
constexpr size_t OFF_WF  = OFF_WB + 3*(size_t)SZ_WB;     // 270336
constexpr size_t OFF_WG  = OFF_WF + 3*(size_t)SZ_WF;     // 417792
constexpr size_t OFF_WC  = OFF_WG + 3*(size_t)SZ_WG;     // 1204224
constexpr size_t OFF_WH  = OFF_WC + 3*(size_t)SZ_WC;     // 1990656  [512][192] nhw1|dhw1|wtw1
constexpr size_t OFF_WH2 = OFF_WH + (size_t)512*192;     // 2088960  [128][256] blockdiag(nhw2,dhw2)
constexpr size_t WS_TOTAL= OFF_WH2 + (size_t)128*256;    // 2121728 bf16 elems

DI short f2b(float f){ unsigned u; __builtin_memcpy(&u,&f,4); u += 0x7fffu + ((u>>16)&1u); return (short)(u>>16); }
DI float b2f(short s){ unsigned u = ((unsigned)(unsigned short)s)<<16; float f; __builtin_memcpy(&f,&u,4); return f; }
DI float sigm(float x){ return 1.f/(1.f+__expf(-x)); }

// ---------------- weight prepass: fp32 -> bf16 MFMA-B-fragment layout ----------------
// frag element t = ((nt*K32 + kt)*64 + lane)*8 + j  <->  W[kt*32 + (lane>>4)*8 + j][nt*16 + (lane&15)]
__global__ __launch_bounds__(256) void prep_weights(
    const float* __restrict__ pbw,  const float* __restrict__ paw1,
    const float* __restrict__ piw1, const float* __restrict__ pfw,
    const float* __restrict__ pgw,  const float* __restrict__ fcw,
    const float* __restrict__ nhw1, const float* __restrict__ nhw2,
    const float* __restrict__ dhw1, const float* __restrict__ dhw2,
    const float* __restrict__ wtw1, short* __restrict__ ws)
{
  size_t t = (size_t)blockIdx.x*256 + threadIdx.x;
  if (t >= WS_TOTAL) return;
  float v = 0.f;
  if (t < OFF_WB) {                                   // [512][80] = paw1 | piw1, K32=16
    int q=(int)t; int ly=q/SZ_WT; int qq=q%SZ_WT;
    int j=qq&7, lane=(qq>>3)&63, tile=qq>>9, kt=tile&15, nt=tile>>4;
    int k=kt*32+((lane>>4)<<3)+j, n=nt*16+(lane&15);
    v = (n<64) ? paw1[((size_t)ly*512+k)*64+n] : piw1[((size_t)ly*512+k)*16+(n-64)];
  } else if (t < OFF_WF) {                            // [512][96] pbw flat (c=k*32+j), K32=16
    int q=(int)(t-OFF_WB); int ly=q/SZ_WB; int qq=q%SZ_WB;
    int j=qq&7, lane=(qq>>3)&63, tile=qq>>9, kt=tile&15, nt=tile>>4;
    int k=kt*32+((lane>>4)<<3)+j, c=nt*16+(lane&15);
    v = pbw[(((size_t)ly*3+(c>>5))*512+k)*32+(c&31)];
  } else if (t < OFF_WG) {                            // [96][512] pfw, K32=3
    int q=(int)(t-OFF_WF); int ly=q/SZ_WF; int qq=q%SZ_WF;
    int j=qq&7, lane=(qq>>3)&63, tile=qq>>9, kt=tile%3, nt=tile/3;
    int k=kt*32+((lane>>4)<<3)+j, n=nt*16+(lane&15);
    v = pfw[((size_t)ly*96+k)*512+n];
  } else if (t < OFF_WC) {                            // [512][512] pgw
    int q=(int)(t-OFF_WG); int ly=q/SZ_WG; int qq=q%SZ_WG;
    int j=qq&7, lane=(qq>>3)&63, tile=qq>>9, kt=tile&15, nt=tile>>4;
    int k=kt*32+((lane>>4)<<3)+j, n=nt*16+(lane&15);
    v = pgw[((size_t)ly*512+k)*512+n];
  } else if (t < OFF_WH) {                            // [512][512] fcw
    int q=(int)(t-OFF_WC); int ly=q/SZ_WC; int qq=q%SZ_WC;
    int j=qq&7, lane=(qq>>3)&63, tile=qq>>9, kt=tile&15, nt=tile>>4;
    int k=kt*32+((lane>>4)<<3)+j, n=nt*16+(lane&15);
    v = fcw[((size_t)ly*512+k)*512+n];
  } else if (t < OFF_WH2) {                           // [512][192] heads hidden
    int qq=(int)(t-OFF_WH);
    int j=qq&7, lane=(qq>>3)&63, tile=qq>>9, kt=tile&15, nt=tile>>4;
    int k=kt*32+((lane>>4)<<3)+j, n=nt*16+(lane&15);
    v = (n<64) ? nhw1[(size_t)k*64+n] : (n<128) ? dhw1[(size_t)k*64+(n-64)] : wtw1[(size_t)k*64+(n-128)];
  } else {                                            // [128][256] blockdiag(nhw2,dhw2), K32=4
    int qq=(int)(t-OFF_WH2);
    int j=qq&7, lane=(qq>>3)&63, tile=qq>>9, kt=tile&3, nt=tile>>2;
    int k=kt*32+((lane>>4)<<3)+j, n=nt*16+(lane&15);
    if (k<64) v = (n<128) ? nhw2[(size_t)k*128+n] : 0.f;
    else      v = (n>=128)? dhw2[(size_t)(k-64)*128+(n-128)] : 0.f;
  }
  ws[t] = f2b(v);
}

// ---------------- fused network ----------------
// 32 rows/block, 1024 threads (16 waves), double-buffered h, 80KB LDS.
// R20 achieved clean traffic + 2 blocks/CU at 8 waves/block but was
// latency-bound (HBM 3%, MfmaUtil 14%) at 4 waves/SIMD. Doubling waves/block
// doubles TLP to the chip max (2 blocks x 16 waves = 32 waves/CU = 8/SIMD),
// requiring VGPR<=64: launch_bounds(1024,4) -> 64-reg alloc (R6-verified);
// live state ~40 regs (acc[2] single-col passes, zero cross-barrier state).
__global__ __launch_bounds__(1024, 4) void pan_main(
  const float* __restrict__ x,
  const float* __restrict__ pbb,  const float* __restrict__ pab1,
  const float* __restrict__ paw2, const float* __restrict__ pab2,
  const float* __restrict__ pib1, const float* __restrict__ piw2,
  const float* __restrict__ pib2, const float* __restrict__ pfb,
  const float* __restrict__ pgb,  const float* __restrict__ fcb,
  const float* __restrict__ bng,  const float* __restrict__ bnb,
  const float* __restrict__ bnm,  const float* __restrict__ bnv,
  const float* __restrict__ nhb1, const float* __restrict__ nhb2,
  const float* __restrict__ dhb1, const float* __restrict__ dhb2,
  const float* __restrict__ wtb1, const float* __restrict__ wtw2,
  const float* __restrict__ wtb2,
  const short* __restrict__ ws, float* __restrict__ out)
{
  __shared__ __align__(16) char lds[81920];
  char* hA = lds;            // current h [32][512] bf16, stride 1024B, byte ^= (row&7)<<4
  char* hB = lds + 32768;    // next h (same layout); heads h1 [32][384B] goes here
  char* sU = lds + 65536;    // sT bf16 [32][80] @0 (5120) | ci f32 [32] @5120 | cwci bf16 [32][32] @5248
  char* sW = lds + 73728;    // weighted [32][128] bf16 swizzled, stride 256B

  const int tid  = threadIdx.x;
  const int wave = tid >> 6;
  const int l    = tid & 63;
  const int lr   = l & 15;
  const int lb   = l >> 4;
  const int swzA = (lr & 7) << 4;
  const size_t row0 = (size_t)blockIdx.x * 32;

  // ---- load x tile -> hA (bf16, swizzled)
  #pragma unroll 2
  for (int c = tid; c < 2048; c += 1024) {
    int row = c >> 6, k0 = (c & 63) << 3;
    const float4* s0 = (const float4*)(x + (row0 + row)*512 + k0);
    float4 f0 = s0[0], f1 = s0[1];
    bf16x8 p;
    p[0]=f2b(f0.x); p[1]=f2b(f0.y); p[2]=f2b(f0.z); p[3]=f2b(f0.w);
    p[4]=f2b(f1.x); p[5]=f2b(f1.y); p[6]=f2b(f1.z); p[7]=f2b(f1.w);
    *(bf16x8*)(hA + row*1024 + ((k0*2) ^ ((row&7)<<4))) = p;
  }
  __syncthreads();

  auto ldA = [&](const char* base, int rt, int kt) -> bf16x8 {
    int row = rt*16 + lr;
    return *(const bf16x8*)(base + row*1024 + ((kt*64 + lb*16) ^ swzA));
  };
  auto ldB = [&](const short* W, int K32, int nt, int kt) -> bf16x8 {
    return *(const bf16x8*)(W + (((size_t)(nt*K32 + kt))*64 + l)*8);
  };
  auto ldH = [&](const char* base, int row, int col) -> float {
    return b2f(*(const short*)(base + row*1024 + ((col*2) ^ ((row&7)<<4))));
  };
  auto stH = [&](char* base, int row, int col, float v) {
    *(short*)(base + row*1024 + ((col*2) ^ ((row&7)<<4))) = f2b(v);
  };
  const f32x4 FZ = {0.f,0.f,0.f,0.f};

  // ================= PAN layers =================
  for (int ly = 0; ly < 3; ++ly) {
    // --- t_all = relu(h @ [paw1|piw1] + b) -> sT  (N=80: 5 col-tiles x 2 row-halves)
    if (wave < 10) {
      const short* W = ws + OFF_WT + (size_t)ly*SZ_WT;
      const int nt = wave % 5, rh = wave / 5;
      f32x4 acc = FZ;
      #pragma unroll 2
      for (int kt=0;kt<16;++kt) {
        bf16x8 b = ldB(W,16,nt,kt);
        acc = MFMA(ldA(hA,rh,kt), b, acc);
      }
      const int col = nt*16 + lr;
      const float bias = (col<64) ? pab1[ly*64+col] : pib1[ly*16+(col-64)];
      #pragma unroll
      for (int jj=0;jj<4;++jj) {
        int row = rh*16 + lb*4 + jj;
        *(short*)(sU + row*160 + col*2) = f2b(fmaxf(acc[jj]+bias, 0.f));
      }
    }
    __syncthreads();
    // --- ci = sigmoid(t2 @ piw2 + b)  (threads 0..31, vectorized reads)
    if (tid < 32) {
      float s = pib2[ly];
      bf16x8 t0 = *(const bf16x8*)(sU + tid*160 + 128);
      bf16x8 t1 = *(const bf16x8*)(sU + tid*160 + 144);
      #pragma unroll
      for (int i=0;i<8;++i) {
        s += b2f(t0[i]) * piw2[ly*16+i];
        s += b2f(t1[i]) * piw2[ly*16+8+i];
      }
      *(float*)(sU + 5120 + tid*4) = sigm(s);
    }
    __syncthreads();
    // --- cwci = sigmoid(t1 @ paw2 + b) * ci  (1024 thr, 1 output/thread)
    {
      const int r = tid>>5, j0 = tid&31;
      float a = pab2[ly*32 + j0];
      #pragma unroll 2
      for (int k8=0;k8<8;++k8) {
        bf16x8 tv8 = *(const bf16x8*)(sU + r*160 + k8*16);
        #pragma unroll
        for (int i8=0;i8<8;++i8)
          a = fmaf(b2f(tv8[i8]), paw2[((size_t)ly*64 + k8*8+i8)*32 + j0], a);
      }
      const float civ = *(const float*)(sU + 5120 + r*4);
      *(short*)(sU + 5248 + (r*32 + j0)*2) = f2b(sigm(a) * civ);
    }
    __syncthreads();
    // --- feats = relu(h @ pbw + b); weighted -> sW  (N=96: 6 tiles x 2 row-halves)
    if (wave < 12) {
      const short* W = ws + OFF_WB + (size_t)ly*SZ_WB;
      const int nt = wave % 6, rh = wave / 6;
      f32x4 acc = FZ;
      #pragma unroll 2
      for (int kt=0;kt<16;++kt) {
        bf16x8 b = ldB(W,16,nt,kt);
        acc = MFMA(ldA(hA,rh,kt), b, acc);
      }
      const int col = nt*16 + lr;
      const float bias = pbb[ly*96 + col];
      #pragma unroll
      for (int jj=0;jj<4;++jj) {
        int row = rh*16 + lb*4 + jj;
        float cc = b2f(*(const short*)(sU + 5248 + (row*32 + (col&31))*2));
        float wv = fmaxf(acc[jj]+bias, 0.f) * cc;
        *(short*)(sW + row*256 + ((col*2) ^ ((row&7)<<4))) = f2b(wv);
      }
    }
    __syncthreads();
    // --- gate = sigmoid(h @ pgw + b); h' = weighted @ pfw + pfb + gate*h
    //     TWO single-col passes/wave (acc[2]=8 regs) -> hB DIRECTLY.
    {
      const short* Wg = ws + OFF_WG + (size_t)ly*SZ_WG;
      const short* Wf = ws + OFF_WF + (size_t)ly*SZ_WF;
      #pragma unroll 1
      for (int c=0; c<2; ++c) {
        const int ct = wave*2 + c;
        f32x4 acc[2];
        #pragma unroll
        for (int rt=0;rt<2;++rt) acc[rt] = FZ;
        #pragma unroll 2
        for (int kt=0;kt<16;++kt) {
          bf16x8 b = ldB(Wg,16, ct, kt);
          #pragma unroll
          for (int rt=0;rt<2;++rt) acc[rt] = MFMA(ldA(hA,rt,kt), b, acc[rt]);
        }
        const int col = ct*16 + lr;
        const float gb = pgb[ly*512+col];
        const float fb = pfb[ly*512+col];
        #pragma unroll
        for (int rt=0;rt<2;++rt)
          #pragma unroll
          for (int jj=0;jj<4;++jj) {
            int row = rt*16 + lb*4 + jj;
            acc[rt][jj] = sigm(acc[rt][jj]+gb)*ldH(hA,row,col) + fb;
          }
        #pragma unroll 1
        for (int kt=0;kt<3;++kt) {   // fused accumulate, K=96, A from sW
          bf16x8 b = ldB(Wf,3, ct, kt);
          #pragma unroll
          for (int rt=0;rt<2;++rt) {
            int row = rt*16 + lr;
            bf16x8 a = *(const bf16x8*)(sW + row*256 + ((kt*64 + lb*16) ^ swzA));
            acc[rt] = MFMA(a,b,acc[rt]);
          }
        }
        #pragma unroll
        for (int rt=0;rt<2;++rt)
          #pragma unroll
          for (int jj=0;jj<4;++jj)
            stH(hB, rt*16 + lb*4 + jj, col, acc[rt][jj]);
      }
    }
    __syncthreads();
    { char* t = hA; hA = hB; hB = t; }
  }

  // ================= FC + BN(eval) + ReLU  x3 =================
  for (int fi=0; fi<3; ++fi) {
    const short* W = ws + OFF_WC + (size_t)fi*SZ_WC;
    #pragma unroll 1
    for (int c=0; c<2; ++c) {
      const int ct = wave*2 + c;
      f32x4 acc[2];
      #pragma unroll
      for (int rt=0;rt<2;++rt) acc[rt] = FZ;
      #pragma unroll 2
      for (int kt=0;kt<16;++kt) {
        bf16x8 b = ldB(W,16, ct, kt);
        #pragma unroll
        for (int rt=0;rt<2;++rt) acc[rt] = MFMA(ldA(hA,rt,kt), b, acc[rt]);
      }
      const int col = ct*16 + lr;
      const float sc = bng[fi*512+col] * rsqrtf(bnv[fi*512+col] + 1e-5f);
      const float of = bnb[fi*512+col] - bnm[fi*512+col]*sc;
      const float bb = fcb[fi*512+col];
      #pragma unroll
      for (int rt=0;rt<2;++rt)
        #pragma unroll
        for (int jj=0;jj<4;++jj)
          stH(hB, rt*16 + lb*4 + jj, col,
              fmaxf((acc[rt][jj] + bb)*sc + of, 0.f));
    }
    __syncthreads();
    { char* t = hA; hA = hB; hB = t; }
  }

  // ================= heads =================
  // h1 = relu(h @ [nhw1|dhw1|wtw1] + b): N=192 = 12 tiles; waves 0..11.
  // Written DIRECTLY to hB, stride 384.
  if (wave < 12) {
    const short* W = ws + OFF_WH;
    f32x4 acc[2];
    #pragma unroll
    for (int rt=0;rt<2;++rt) acc[rt] = FZ;
    #pragma unroll 2
    for (int kt=0;kt<16;++kt) {
      bf16x8 b = ldB(W,16,wave,kt);
      #pragma unroll
      for (int rt=0;rt<2;++rt) acc[rt] = MFMA(ldA(hA,rt,kt), b, acc[rt]);
    }
    const int col = wave*16 + lr;
    const float bias = (col<64) ? nhb1[col] : (col<128) ? dhb1[col-64] : wtb1[col-128];
    #pragma unroll
    for (int rt=0;rt<2;++rt)
      #pragma unroll
      for (int jj=0;jj<4;++jj) {
        int row = rt*16 + lb*4 + jj;
        *(short*)(hB + row*384 + ((col*2) ^ ((row&7)<<4))) =
            f2b(fmaxf(acc[rt][jj]+bias, 0.f));
      }
  }
  __syncthreads();
  { // logits = h1[:, :128] @ blockdiag(nhw2,dhw2): 16 tiles = 16 waves x 1
    const short* W2 = ws + OFF_WH2;
    f32x4 acc[2];
    #pragma unroll
    for (int rt=0;rt<2;++rt) acc[rt] = FZ;
    #pragma unroll 2
    for (int kt=0;kt<4;++kt) {
      bf16x8 b = ldB(W2,4, wave, kt);
      #pragma unroll
      for (int rt=0;rt<2;++rt) {
        int row = rt*16 + lr;
        bf16x8 a = *(const bf16x8*)(hB + row*384 + ((kt*64 + lb*16) ^ swzA));
        acc[rt] = MFMA(a,b,acc[rt]);
      }
    }
    const int col2 = wave*16 + lr;
    const bool isn = col2 < 128;
    const int cc = col2 & 127;
    const float bias = isn ? nhb2[cc] : dhb2[cc];
    const size_t obase = isn ? (size_t)0 : (size_t)4194304;
    #pragma unroll
    for (int rt=0;rt<2;++rt)
      #pragma unroll
      for (int jj=0;jj<4;++jj) {
        int row = rt*16 + lb*4 + jj;
        size_t rg = row0 + row;
        float2 caps = *(const float2*)(x + rg*512 + 508);   // (s_nurse_max, s_doctor_max)
        int cap = (int)(isn ? caps.x : caps.y);
        float v = acc[rt][jj] + bias;
        out[obase + rg*128 + cc] = (cc <= cap) ? v : -1e9f;
      }
  }
  // wait_time = h1[:, 128:192] @ wtw2 + b (read-only on h1)
  if (tid < 32) {
    float s = wtb2[0];
    #pragma unroll 2
    for (int k8=0;k8<8;++k8) {
      bf16x8 hv = *(const bf16x8*)(hB + tid*384 + ((256 + k8*16) ^ ((tid&7)<<4)));
      #pragma unroll
      for (int i=0;i<8;++i) s += b2f(hv[i]) * wtw2[k8*8+i];
    }
    out[(size_t)8388608 + row0 + tid] = s;
  }
}

extern "C" void kernel_launch(void* const* d_in, const int* in_sizes, int n_in,
                              void* d_out, int out_size, void* d_ws, size_t ws_size,
                              hipStream_t stream) {
  const float* x    = (const float*)d_in[0];
  const float* pbw  = (const float*)d_in[1];
  const float* pbb  = (const float*)d_in[2];
  const float* paw1 = (const float*)d_in[3];
  const float* pab1 = (const float*)d_in[4];
  const float* paw2 = (const float*)d_in[5];
  const float* pab2 = (const float*)d_in[6];
  const float* piw1 = (const float*)d_in[7];
  const float* pib1 = (const float*)d_in[8];
  const float* piw2 = (const float*)d_in[9];
  const float* pib2 = (const float*)d_in[10];
  const float* pfw  = (const float*)d_in[11];
  const float* pfb  = (const float*)d_in[12];
  const float* pgw  = (const float*)d_in[13];
  const float* pgb  = (const float*)d_in[14];
  const float* fcw  = (const float*)d_in[15];
  const float* fcb  = (const float*)d_in[16];
  const float* bng  = (const float*)d_in[17];
  const float* bnb  = (const float*)d_in[18];
  const float* bnm  = (const float*)d_in[19];
  const float* bnv  = (const float*)d_in[20];
  const float* nhw1 = (const float*)d_in[21];
  const float* nhb1 = (const float*)d_in[22];
  const float* nhw2 = (const float*)d_in[23];
  const float* nhb2 = (const float*)d_in[24];
  const float* dhw1 = (const float*)d_in[25];
  const float* dhb1 = (const float*)d_in[26];
  const float* dhw2 = (const float*)d_in[27];
  const float* dhb2 = (const float*)d_in[28];
  const float* wtw1 = (const float*)d_in[29];
  const float* wtb1 = (const float*)d_in[30];
  const float* wtw2 = (const float*)d_in[31];
  const float* wtb2 = (const float*)d_in[32];
  short* ws  = (short*)d_ws;
  float* out = (float*)d_out;

  prep_weights<<<(int)((WS_TOTAL + 255)/256), 256, 0, stream>>>(
      pbw, paw1, piw1, pfw, pgw, fcw, nhw1, nhw2, dhw1, dhw2, wtw1, ws);
  pan_main<<<1024, 1024, 0, stream>>>(
      x, pbb, pab1, paw2, pab2, pib1, piw2, pib2, pfb, pgb, fcb,
      bng, bnb, bnm, bnv, nhb1, nhb2, dhb1, dhb2, wtb1, wtw2, wtb2, ws, out);
}